// Round 14
// baseline (196.506 us; speedup 1.0000x reference)
//
#include <hip/hip_runtime.h>
#include <hip/hip_bf16.h>
#include <math.h>

#define M_TOTAL 16384   // B*S = 4*4096
#define D_MODEL 1024
#define N_QKV   3072
#define CURV    0.15f
#define EPS_F   1e-6f

typedef __attribute__((ext_vector_type(8))) short short8v;
typedef __attribute__((ext_vector_type(4))) float f32x4;

__device__ __forceinline__ void gl_lds16(const void* g, void* l) {
    __builtin_amdgcn_global_load_lds(
        (const __attribute__((address_space(1))) void*)g,
        (__attribute__((address_space(3))) void*)l, 16, 0, 0);
}
__device__ __forceinline__ unsigned short f2bf_bits(float x) {
    __hip_bfloat16 t = __float2bfloat16(x);
    return *(unsigned short*)&t;
}
__device__ __forceinline__ float bf2f(unsigned short u) {
    return __uint_as_float(((unsigned)u) << 16);
}

// ---------------------------------------------------------------------------
// cast fp32 -> bf16, 4 elems/thread
// ---------------------------------------------------------------------------
__global__ __launch_bounds__(256)
void cast_f32_bf16(const float* __restrict__ in, unsigned short* __restrict__ out,
                   int ngroups)
{
    int i = blockIdx.x * 256 + threadIdx.x;
    if (i >= ngroups) return;
    float4 u = ((const float4*)in)[i];
    ushort4 r;
    r.x = f2bf_bits(u.x); r.y = f2bf_bits(u.y);
    r.z = f2bf_bits(u.z); r.w = f2bf_bits(u.w);
    ((ushort4*)out)[i] = r;
}

// ---------------------------------------------------------------------------
// transpose + cast: W[K][N] fp32  ->  Wt[N][K] bf16.
// ---------------------------------------------------------------------------
__global__ __launch_bounds__(256)
void transpose_cast(const float* __restrict__ W, unsigned short* __restrict__ Wt,
                    int K, int N)
{
    __shared__ float tile[32][33];
    const int n0 = blockIdx.x * 32;
    const int k0 = blockIdx.y * 32;
    const int tx = threadIdx.x & 31;
    const int ty = threadIdx.x >> 5;
    #pragma unroll
    for (int i = 0; i < 32; i += 8)
        tile[ty + i][tx] = W[(size_t)(k0 + ty + i) * N + n0 + tx];
    __syncthreads();
    #pragma unroll
    for (int i = 0; i < 32; i += 8)
        Wt[(size_t)(n0 + ty + i) * K + k0 + tx] = f2bf_bits(tile[tx][ty + i]);
}

// ---------------------------------------------------------------------------
// 256x256 bf16 MFMA GEMM — R14: faithful m201 8-phase template.
// Per phase: [ds_reads (same-phase operands) -> stage -> (lgkm(8) if 12 reads)
//            -> BARRIER -> lgkmcnt(0) -> setprio(1) 16xMFMA setprio(0) -> BARRIER]
// Mechanism: post-barrier lgkm(0) drains at each wave's own LDS-FCFS position
// -> wave-0's MFMAs overlap waves 1-7's pending reads (fine interleave, m196).
// Reads/phase {12,4,8,0}; stages: p2 -> B0,B1(T+2), p3 -> A0,A1(T+2) (regions
// retired: B at p1's lgkm(0)+bar, A at p2's lgkm(0)+bar). Boundary vmcnt(8)
// COUNTED (m218: never drain to 0 in main loop) — 8 = T+2's in-flight loads,
// in-order retirement guarantees T+1 resident. Tail (T+2>=nt): vmcnt(0).
// ---------------------------------------------------------------------------
template<int OUT_BF16>
__global__ __launch_bounds__(512, 2)
void gemm256_8ph(const unsigned short* __restrict__ A,
                 const unsigned short* __restrict__ Bt,
                 const float* __restrict__ bias,
                 void* __restrict__ Cout,
                 int M, int N, int K, int nbx)
{
    __shared__ __align__(16) short smem_s[65536];   // 128 KiB

    const int t    = threadIdx.x;
    const int w    = t >> 6;
    const int lane = t & 63;
    const int wm   = w >> 2;
    const int wn   = w & 3;
    const int lr   = lane & 15;
    const int hi   = lane >> 4;
    const int lo7  = lane & 7;

    const int nwg  = gridDim.x;
    const int orig = blockIdx.x;
    const int wgid = (orig & 7) * (nwg >> 3) + (orig >> 3);
    const int by = wgid / nbx, bx = wgid % nbx;
    const int bm0 = by * 256, bn0 = bx * 256;

    const int nt = K >> 6;

    const int srow = t >> 3;
    const int scol = ((t & 7) ^ (srow & 7)) * 8;
    const unsigned short* Ag = A  + (size_t)(bm0 + srow) * K + scol;
    const unsigned short* Bg = Bt + (size_t)(bn0 + srow) * K + scol;
    const int wbase = w * 1024;

    auto STAGE = [&](int which, int half, int tile) {
        const unsigned short* g0 = (which ? Bg : Ag)
                                 + (size_t)(half * 128) * K + (size_t)tile * 64;
        char* d0 = (char*)smem_s + ((tile & 1) * 65536 + which * 32768
                                    + half * 16384 + wbase);
        gl_lds16(g0,                d0);
        gl_lds16(g0 + (size_t)64*K, d0 + 8192);
    };

    short8v a[8][2], b[4][2];
    f32x4 acc[8][4] = {};

    auto LDA = [&](int buf, int m, int ks) {
        a[m][ks] = *(const short8v*)&smem_s[buf*32768 + wm*8192
                        + (m*16 + lr)*64 + (((ks*4 + hi) ^ lo7) * 8)];
    };
    auto LDB = [&](int buf, int n, int ks) {
        b[n][ks] = *(const short8v*)&smem_s[buf*32768 + 16384 + (wn>>1)*8192
                        + ((wn&1)*64 + n*16 + lr)*64 + (((ks*4 + hi) ^ lo7) * 8)];
    };
    auto QUAD = [&](int mlo, int nlo) {      // ks-outer (R12, neutral-safe)
        __builtin_amdgcn_s_setprio(1);
        #pragma unroll
        for (int ks = 0; ks < 2; ++ks)
            #pragma unroll
            for (int mi = 0; mi < 4; ++mi)
                #pragma unroll
                for (int ni = 0; ni < 2; ++ni)
                    acc[mlo+mi][nlo+ni] = __builtin_amdgcn_mfma_f32_16x16x32_bf16(
                        a[mlo+mi][ks], b[nlo+ni][ks], acc[mlo+mi][nlo+ni], 0, 0, 0);
        __builtin_amdgcn_s_setprio(0);
    };

    // ---- prologue: stage tiles 0,1 (16 gl_lds); vmcnt(8) -> tile0 resident --
    STAGE(0,0,0); STAGE(0,1,0); STAGE(1,0,0); STAGE(1,1,0);
    STAGE(0,0,1); STAGE(0,1,1); STAGE(1,0,1); STAGE(1,1,1);
    asm volatile("s_waitcnt vmcnt(8)" ::: "memory");
    __builtin_amdgcn_s_barrier();

    for (int T = 0; T < nt; ++T) {
        const int buf  = T & 1;
        const bool has2 = (T + 2 < nt);

        // ---- p0: 12 reads (a0-3, b01); predrain lgkm(8); BAR; lgkm(0); Q00 --
        #pragma unroll
        for (int m = 0; m < 4; ++m) { LDA(buf,m,0); LDA(buf,m,1); }
        LDB(buf,0,0); LDB(buf,0,1); LDB(buf,1,0); LDB(buf,1,1);
        asm volatile("s_waitcnt lgkmcnt(8)" ::: "memory");
        __builtin_amdgcn_s_barrier();
        asm volatile("s_waitcnt lgkmcnt(0)" ::: "memory");
        __builtin_amdgcn_sched_barrier(0);
        QUAD(0,0);
        __builtin_amdgcn_s_barrier();
        // ---- p1: 4 reads (b23); BAR; lgkm(0); Q02 ----
        LDB(buf,2,0); LDB(buf,2,1); LDB(buf,3,0); LDB(buf,3,1);
        __builtin_amdgcn_s_barrier();
        asm volatile("s_waitcnt lgkmcnt(0)" ::: "memory");
        __builtin_amdgcn_sched_barrier(0);
        QUAD(0,2);
        __builtin_amdgcn_s_barrier();        // B-region reads retired (all waves)
        // ---- p2: 8 reads (a4-7); stage B0,B1(T+2); BAR; lgkm(0); Q40 ----
        #pragma unroll
        for (int m = 4; m < 8; ++m) { LDA(buf,m,0); LDA(buf,m,1); }
        if (has2) { STAGE(1,0,T+2); STAGE(1,1,T+2); }
        __builtin_amdgcn_s_barrier();
        asm volatile("s_waitcnt lgkmcnt(0)" ::: "memory");
        __builtin_amdgcn_sched_barrier(0);
        QUAD(4,0);
        __builtin_amdgcn_s_barrier();        // A-region reads retired (all waves)
        // ---- p3: 0 reads; stage A0,A1(T+2); Q42; counted vmcnt boundary ----
        if (has2) { STAGE(0,0,T+2); STAGE(0,1,T+2); }
        __builtin_amdgcn_sched_barrier(0);
        QUAD(4,2);
        if (has2) { asm volatile("s_waitcnt vmcnt(8)" ::: "memory"); }
        else      { asm volatile("s_waitcnt vmcnt(0)" ::: "memory"); }
        __builtin_amdgcn_s_barrier();        // tile T+1 resident for all
    }

    // ---- epilogue: C/D layout col=lane&15, row=hi*4+j ----
    const int r0 = bm0 + wm*128 + hi*4;
    const int cb = bn0 + wn*64 + lr;
    float bv[4];
    #pragma unroll
    for (int n = 0; n < 4; ++n) bv[n] = bias[cb + n*16];
    if (OUT_BF16) {
        unsigned short* Cb = (unsigned short*)Cout;
        #pragma unroll
        for (int m = 0; m < 8; ++m)
            #pragma unroll
            for (int j = 0; j < 4; ++j) {
                unsigned short* rp = Cb + (size_t)(r0 + m*16 + j) * N;
                #pragma unroll
                for (int n = 0; n < 4; ++n)
                    rp[cb + n*16] = f2bf_bits(acc[m][n][j] + bv[n]);
            }
    } else {
        float* Cf = (float*)Cout;
        #pragma unroll
        for (int m = 0; m < 8; ++m)
            #pragma unroll
            for (int j = 0; j < 4; ++j) {
                float* rp = Cf + (size_t)(r0 + m*16 + j) * N;
                #pragma unroll
                for (int n = 0; n < 4; ++n)
                    rp[cb + n*16] = acc[m][n][j] + bv[n];
            }
    }
}

// ---------------------------------------------------------------------------
// R9 attention (unchanged): one wave per position, all-register, no LDS.
// ---------------------------------------------------------------------------
__global__ __launch_bounds__(256)
void attn_mfma_kernel(const unsigned short* __restrict__ qkv,
                      unsigned short* __restrict__ aout)
{
    const int l  = threadIdx.x & 63;
    const int wv = threadIdx.x >> 6;
    const int p  = blockIdx.x * 4 + wv;
    const int lr = l & 15;
    const int hi = l >> 4;
    const unsigned short* base = qkv + (size_t)p * N_QKV;

    short8v qf0 = *(const short8v*)(base +        lr*64 +      hi*8);
    short8v qf1 = *(const short8v*)(base +        lr*64 + 32 + hi*8);
    short8v kf0 = *(const short8v*)(base + 1024 + lr*64 +      hi*8);
    short8v kf1 = *(const short8v*)(base + 1024 + lr*64 + 32 + hi*8);

    f32x4 s = {};
    s = __builtin_amdgcn_mfma_f32_16x16x32_bf16(kf0, qf0, s, 0, 0, 0);
    s = __builtin_amdgcn_mfma_f32_16x16x32_bf16(kf1, qf1, s, 0, 0, 0);

    float qsq = 0.f, ksq = 0.f;
    #pragma unroll
    for (int i = 0; i < 8; ++i) {
        float q0 = bf2f((unsigned short)qf0[i]), q1 = bf2f((unsigned short)qf1[i]);
        float k0 = bf2f((unsigned short)kf0[i]), k1 = bf2f((unsigned short)kf1[i]);
        qsq = fmaf(q0, q0, fmaf(q1, q1, qsq));
        ksq = fmaf(k0, k0, fmaf(k1, k1, ksq));
    }
    qsq += __shfl_xor(qsq, 16); qsq += __shfl_xor(qsq, 32);
    ksq += __shfl_xor(ksq, 16); ksq += __shfl_xor(ksq, 32);

    const float mq = sqrtf(qsq);

    float P[4];
    #pragma unroll
    for (int j = 0; j < 4; ++j) {
        float ksg = __shfl(ksq, hi * 4 + j);
        float dsq = fmaxf(qsq + ksg - 2.f * s[j], 0.f);
        dsq = dsq * (1.f + CURV * cosf(sqrtf(dsq + EPS_F)));
        P[j] = mq * sqrtf(ksg) / (dsq + EPS_F);
    }
    float mx = fmaxf(fmaxf(P[0], P[1]), fmaxf(P[2], P[3]));
    mx = fmaxf(mx, __shfl_xor(mx, 16));
    mx = fmaxf(mx, __shfl_xor(mx, 32));
    float sm = 0.f;
    #pragma unroll
    for (int j = 0; j < 4; ++j) { P[j] = expf(P[j] - mx); sm += P[j]; }
    sm += __shfl_xor(sm, 16); sm += __shfl_xor(sm, 32);
    const float inv = 1.f / sm;

    unsigned int w0 = (unsigned)f2bf_bits(P[0] * inv)
                    | ((unsigned)f2bf_bits(P[1] * inv) << 16);
    unsigned int w1 = (unsigned)f2bf_bits(P[2] * inv)
                    | ((unsigned)f2bf_bits(P[3] * inv) << 16);
    const int s0 = lr + (((2 * hi)     & 3) << 4);
    const int s1 = lr + (((2 * hi + 1) & 3) << 4);
    unsigned int a0 = __shfl((int)w0, s0), a1 = __shfl((int)w1, s0);
    unsigned int a2 = __shfl((int)w0, s1), a3 = __shfl((int)w1, s1);
    if (hi >= 2) { a0 = a1 = a2 = a3 = 0; }
    unsigned int pa_u[4] = {a0, a1, a2, a3};
    short8v pa = *(short8v*)pa_u;

    const unsigned short* vb = base + 2048;
    unsigned short* orow = aout + (size_t)p * D_MODEL;
    #pragma unroll
    for (int c = 0; c < 4; ++c) {
        unsigned int bu[4];
        #pragma unroll
        for (int e2 = 0; e2 < 4; ++e2) {
            int g0 = (hi * 8 + e2 * 2) & 15;
            int g1 = (hi * 8 + e2 * 2 + 1) & 15;
            unsigned int lo = vb[g0 * 64 + c * 16 + lr];
            unsigned int hi16 = vb[g1 * 64 + c * 16 + lr];
            bu[e2] = lo | (hi16 << 16);
        }
        short8v bv = *(short8v*)bu;
        f32x4 o = {};
        o = __builtin_amdgcn_mfma_f32_16x16x32_bf16(pa, bv, o, 0, 0, 0);
        #pragma unroll
        for (int j = 0; j < 4; ++j)
            orow[(hi * 4 + j) * 64 + c * 16 + lr] = f2bf_bits(o[j]);
    }
}

// ---------------------------------------------------------------------------
extern "C" void kernel_launch(void* const* d_in, const int* in_sizes, int n_in,
                              void* d_out, int out_size, void* d_ws, size_t ws_size,
                              hipStream_t stream)
{
    const float* x     = (const float*)d_in[0];   // 16384 x 1024
    const float* W_qkv = (const float*)d_in[1];   // 1024 x 3072
    const float* b_qkv = (const float*)d_in[2];   // 3072
    const float* W_out = (const float*)d_in[3];   // 1024 x 1024
    const float* b_out = (const float*)d_in[4];   // 1024
    float* out = (float*)d_out;                   // 16384 x 1024

    // workspace: [0,96M) qkv bf16 | [96M,128M) xb/ab bf16 | Wt1 6M | Wt2 2M
    char* ws = (char*)d_ws;
    unsigned short* qkvb = (unsigned short*)ws;
    unsigned short* xb   = (unsigned short*)(ws + (size_t)M_TOTAL * N_QKV * 2);
    unsigned short* ab   = xb;   // alias: xb dead after GEMM1
    unsigned short* Wt1  = (unsigned short*)(ws + (size_t)M_TOTAL * N_QKV * 2
                                                + (size_t)M_TOTAL * D_MODEL * 2);
    unsigned short* Wt2  = Wt1 + (size_t)N_QKV * D_MODEL;

    // 0a) cast x -> bf16
    {
        int ngroups = M_TOTAL * D_MODEL / 4;
        cast_f32_bf16<<<ngroups / 256, 256, 0, stream>>>(x, xb, ngroups);
    }
    // 0b) transpose+cast weights
    {
        dim3 g(N_QKV / 32, D_MODEL / 32);
        transpose_cast<<<g, 256, 0, stream>>>(W_qkv, Wt1, D_MODEL, N_QKV);
        dim3 g2(D_MODEL / 32, D_MODEL / 32);
        transpose_cast<<<g2, 256, 0, stream>>>(W_out, Wt2, D_MODEL, D_MODEL);
    }

    // 1) qkv = x @ W_qkv + b_qkv  (bf16 out)
    {
        int nbx = N_QKV / 256;                 // 12
        int nwg = (M_TOTAL / 256) * nbx;       // 768 (%8==0)
        gemm256_8ph<1><<<nwg, 512, 0, stream>>>(xb, Wt1, b_qkv, qkvb,
                                                M_TOTAL, N_QKV, D_MODEL, nbx);
    }

    // 2) per-position head attention — 1 wave/position, 4 positions/block
    attn_mfma_kernel<<<M_TOTAL / 4, 256, 0, stream>>>(qkvb, ab);

    // 3) out = ab @ W_out + b_out  (fp32 out)
    {
        int nbx = D_MODEL / 256;               // 4
        int nwg = (M_TOTAL / 256) * nbx;       // 256 (%8==0)
        gemm256_8ph<0><<<nwg, 512, 0, stream>>>(ab, Wt2, b_out, out,
                                                M_TOTAL, D_MODEL, D_MODEL, nbx);
    }
}

// Round 15
// 190.507 us; speedup vs baseline: 1.0315x; 1.0315x over previous
//
#include <hip/hip_runtime.h>
#include <hip/hip_bf16.h>
#include <math.h>

#define M_TOTAL 16384   // B*S = 4*4096
#define D_MODEL 1024
#define N_QKV   3072
#define CURV    0.15f
#define EPS_F   1e-6f

typedef __attribute__((ext_vector_type(8))) short short8v;
typedef __attribute__((ext_vector_type(4))) float f32x4;

__device__ __forceinline__ void gl_lds16(const void* g, void* l) {
    __builtin_amdgcn_global_load_lds(
        (const __attribute__((address_space(1))) void*)g,
        (__attribute__((address_space(3))) void*)l, 16, 0, 0);
}
__device__ __forceinline__ unsigned short f2bf_bits(float x) {
    __hip_bfloat16 t = __float2bfloat16(x);
    return *(unsigned short*)&t;
}
__device__ __forceinline__ float bf2f(unsigned short u) {
    return __uint_as_float(((unsigned)u) << 16);
}

// ---------------------------------------------------------------------------
// cast fp32 -> bf16, 4 elems/thread
// ---------------------------------------------------------------------------
__global__ __launch_bounds__(256)
void cast_f32_bf16(const float* __restrict__ in, unsigned short* __restrict__ out,
                   int ngroups)
{
    int i = blockIdx.x * 256 + threadIdx.x;
    if (i >= ngroups) return;
    float4 u = ((const float4*)in)[i];
    ushort4 r;
    r.x = f2bf_bits(u.x); r.y = f2bf_bits(u.y);
    r.z = f2bf_bits(u.z); r.w = f2bf_bits(u.w);
    ((ushort4*)out)[i] = r;
}

// ---------------------------------------------------------------------------
// transpose + cast: W[K][N] fp32  ->  Wt[N][K] bf16.
// ---------------------------------------------------------------------------
__global__ __launch_bounds__(256)
void transpose_cast(const float* __restrict__ W, unsigned short* __restrict__ Wt,
                    int K, int N)
{
    __shared__ float tile[32][33];
    const int n0 = blockIdx.x * 32;
    const int k0 = blockIdx.y * 32;
    const int tx = threadIdx.x & 31;
    const int ty = threadIdx.x >> 5;
    #pragma unroll
    for (int i = 0; i < 32; i += 8)
        tile[ty + i][tx] = W[(size_t)(k0 + ty + i) * N + n0 + tx];
    __syncthreads();
    #pragma unroll
    for (int i = 0; i < 32; i += 8)
        Wt[(size_t)(n0 + ty + i) * K + k0 + tx] = f2bf_bits(tile[tx][ty + i]);
}

// ---------------------------------------------------------------------------
// 256x256 bf16 MFMA GEMM — R13 (measured best: 114.3us GEMM1, 38% MfmaUtil):
// balanced-phase schedule, reads 8/4/6/6 per phase consumed one phase later
// via counted lgkmcnt; buf^1 residency gate (vmcnt(0)+BAR1) at end-of-p1;
// two barriers/tile. Conflict-free XOR swizzle via pre-swizzled source.
//   p0: issue b23+a45 -> lgkm(8) -> Q(0,0)
//   p1: issue a67 -> lgkm(8) -> Q(0,2) -> vmcnt(0) -> BAR1 -> STAGE B(T+2)
//   p2: issue next a0-2 -> lgkm(6|0) -> Q(4,0) -> BAR2 -> STAGE A(T+2)
//   p3: issue next a3,b01 -> Q(4,2)
// Hazards: buf.B frag reads consumed before BAR1 (gates stage B); buf.A
// before BAR2 (gates stage A); buf^1 reads precede its restaging barriers.
// ---------------------------------------------------------------------------
template<int OUT_BF16>
__global__ __launch_bounds__(512, 2)
void gemm256_8ph(const unsigned short* __restrict__ A,
                 const unsigned short* __restrict__ Bt,
                 const float* __restrict__ bias,
                 void* __restrict__ Cout,
                 int M, int N, int K, int nbx)
{
    __shared__ __align__(16) short smem_s[65536];   // 128 KiB

    const int t    = threadIdx.x;
    const int w    = t >> 6;
    const int lane = t & 63;
    const int wm   = w >> 2;
    const int wn   = w & 3;
    const int lr   = lane & 15;
    const int hi   = lane >> 4;
    const int lo7  = lane & 7;

    const int nwg  = gridDim.x;
    const int orig = blockIdx.x;
    const int wgid = (orig & 7) * (nwg >> 3) + (orig >> 3);
    const int by = wgid / nbx, bx = wgid % nbx;
    const int bm0 = by * 256, bn0 = bx * 256;

    const int nt = K >> 6;

    const int srow = t >> 3;
    const int scol = ((t & 7) ^ (srow & 7)) * 8;
    const unsigned short* Ag = A  + (size_t)(bm0 + srow) * K + scol;
    const unsigned short* Bg = Bt + (size_t)(bn0 + srow) * K + scol;
    const int wbase = w * 1024;

    auto STAGE = [&](int which, int half, int tile) {
        const unsigned short* g0 = (which ? Bg : Ag)
                                 + (size_t)(half * 128) * K + (size_t)tile * 64;
        char* d0 = (char*)smem_s + ((tile & 1) * 65536 + which * 32768
                                    + half * 16384 + wbase);
        gl_lds16(g0,                d0);
        gl_lds16(g0 + (size_t)64*K, d0 + 8192);
    };

    short8v a[8][2], b[4][2];
    f32x4 acc[8][4] = {};

    auto LDA = [&](int buf, int m, int ks) {
        a[m][ks] = *(const short8v*)&smem_s[buf*32768 + wm*8192
                        + (m*16 + lr)*64 + (((ks*4 + hi) ^ lo7) * 8)];
    };
    auto LDB = [&](int buf, int n, int ks) {
        b[n][ks] = *(const short8v*)&smem_s[buf*32768 + 16384 + (wn>>1)*8192
                        + ((wn&1)*64 + n*16 + lr)*64 + (((ks*4 + hi) ^ lo7) * 8)];
    };
    auto QUAD = [&](int mlo, int nlo) {      // ks-outer (R12, neutral-safe)
        __builtin_amdgcn_s_setprio(1);
        #pragma unroll
        for (int ks = 0; ks < 2; ++ks)
            #pragma unroll
            for (int mi = 0; mi < 4; ++mi)
                #pragma unroll
                for (int ni = 0; ni < 2; ++ni)
                    acc[mlo+mi][nlo+ni] = __builtin_amdgcn_mfma_f32_16x16x32_bf16(
                        a[mlo+mi][ks], b[nlo+ni][ks], acc[mlo+mi][nlo+ni], 0, 0, 0);
        __builtin_amdgcn_s_setprio(0);
    };

    // ---- prologue: stage tiles 0,1; tile 0 resident; preload 12 frags ----
    STAGE(0,0,0); STAGE(0,1,0); STAGE(1,0,0); STAGE(1,1,0);
    STAGE(0,0,1); STAGE(0,1,1); STAGE(1,0,1); STAGE(1,1,1);
    asm volatile("s_waitcnt vmcnt(8)" ::: "memory");
    __builtin_amdgcn_s_barrier();
    #pragma unroll
    for (int m = 0; m < 4; ++m) { LDA(0,m,0); LDA(0,m,1); }
    LDB(0,0,0); LDB(0,0,1); LDB(0,1,0); LDB(0,1,1);   // 12 outstanding

    for (int T = 0; T < nt; ++T) {
        const int buf  = T & 1;
        const int nbuf = buf ^ 1;
        const bool has1 = (T + 1 < nt);
        const bool has2 = (T + 2 < nt);

        // ---- p0: issue b23+a45 (8); retire prior 12 (keep 8); Q(0,0) ----
        LDB(buf,2,0); LDB(buf,2,1); LDB(buf,3,0); LDB(buf,3,1);
        LDA(buf,4,0); LDA(buf,4,1); LDA(buf,5,0); LDA(buf,5,1);
        asm volatile("s_waitcnt lgkmcnt(8)" ::: "memory");
        __builtin_amdgcn_sched_barrier(0);
        QUAD(0,0);
        // ---- p1: issue a67 (4); retire b23 (keep a45+a67=8); Q(0,2);
        //      vmcnt(0): T+1 stages drained; BAR1; stage B(T+2) ----
        LDA(buf,6,0); LDA(buf,6,1); LDA(buf,7,0); LDA(buf,7,1);
        asm volatile("s_waitcnt lgkmcnt(8)" ::: "memory");
        __builtin_amdgcn_sched_barrier(0);
        QUAD(0,2);
        asm volatile("s_waitcnt vmcnt(0)" ::: "memory");
        __builtin_amdgcn_s_barrier();        // BAR1: T+1 resident for all;
        if (has2) { STAGE(1,0,T+2); STAGE(1,1,T+2); }   // buf.B reads done
        // ---- p2: issue next-tile a0-2 (6); retire a4-7; Q(4,0); BAR2 ----
        if (has1) {
            LDA(nbuf,0,0); LDA(nbuf,0,1); LDA(nbuf,1,0); LDA(nbuf,1,1);
            LDA(nbuf,2,0); LDA(nbuf,2,1);
            asm volatile("s_waitcnt lgkmcnt(6)" ::: "memory");
        } else {
            asm volatile("s_waitcnt lgkmcnt(0)" ::: "memory");
        }
        __builtin_amdgcn_sched_barrier(0);
        QUAD(4,0);
        __builtin_amdgcn_s_barrier();        // BAR2: buf.A reads done
        if (has2) { STAGE(0,0,T+2); STAGE(0,1,T+2); }
        // ---- p3: issue next-tile a3,b01 (6); Q(4,2) ----
        if (has1) {
            LDA(nbuf,3,0); LDA(nbuf,3,1);
            LDB(nbuf,0,0); LDB(nbuf,0,1); LDB(nbuf,1,0); LDB(nbuf,1,1);
        }
        __builtin_amdgcn_sched_barrier(0);   // pin: reads issue before Q(4,2)
        QUAD(4,2);
    }

    // ---- epilogue: C/D layout col=lane&15, row=hi*4+j ----
    const int r0 = bm0 + wm*128 + hi*4;
    const int cb = bn0 + wn*64 + lr;
    float bv[4];
    #pragma unroll
    for (int n = 0; n < 4; ++n) bv[n] = bias[cb + n*16];
    if (OUT_BF16) {
        unsigned short* Cb = (unsigned short*)Cout;
        #pragma unroll
        for (int m = 0; m < 8; ++m)
            #pragma unroll
            for (int j = 0; j < 4; ++j) {
                unsigned short* rp = Cb + (size_t)(r0 + m*16 + j) * N;
                #pragma unroll
                for (int n = 0; n < 4; ++n)
                    rp[cb + n*16] = f2bf_bits(acc[m][n][j] + bv[n]);
            }
    } else {
        float* Cf = (float*)Cout;
        #pragma unroll
        for (int m = 0; m < 8; ++m)
            #pragma unroll
            for (int j = 0; j < 4; ++j) {
                float* rp = Cf + (size_t)(r0 + m*16 + j) * N;
                #pragma unroll
                for (int n = 0; n < 4; ++n)
                    rp[cb + n*16] = acc[m][n][j] + bv[n];
            }
    }
}

// ---------------------------------------------------------------------------
// R9 attention (unchanged): one wave per position, all-register, no LDS.
// ---------------------------------------------------------------------------
__global__ __launch_bounds__(256)
void attn_mfma_kernel(const unsigned short* __restrict__ qkv,
                      unsigned short* __restrict__ aout)
{
    const int l  = threadIdx.x & 63;
    const int wv = threadIdx.x >> 6;
    const int p  = blockIdx.x * 4 + wv;
    const int lr = l & 15;
    const int hi = l >> 4;
    const unsigned short* base = qkv + (size_t)p * N_QKV;

    short8v qf0 = *(const short8v*)(base +        lr*64 +      hi*8);
    short8v qf1 = *(const short8v*)(base +        lr*64 + 32 + hi*8);
    short8v kf0 = *(const short8v*)(base + 1024 + lr*64 +      hi*8);
    short8v kf1 = *(const short8v*)(base + 1024 + lr*64 + 32 + hi*8);

    f32x4 s = {};
    s = __builtin_amdgcn_mfma_f32_16x16x32_bf16(kf0, qf0, s, 0, 0, 0);
    s = __builtin_amdgcn_mfma_f32_16x16x32_bf16(kf1, qf1, s, 0, 0, 0);

    float qsq = 0.f, ksq = 0.f;
    #pragma unroll
    for (int i = 0; i < 8; ++i) {
        float q0 = bf2f((unsigned short)qf0[i]), q1 = bf2f((unsigned short)qf1[i]);
        float k0 = bf2f((unsigned short)kf0[i]), k1 = bf2f((unsigned short)kf1[i]);
        qsq = fmaf(q0, q0, fmaf(q1, q1, qsq));
        ksq = fmaf(k0, k0, fmaf(k1, k1, ksq));
    }
    qsq += __shfl_xor(qsq, 16); qsq += __shfl_xor(qsq, 32);
    ksq += __shfl_xor(ksq, 16); ksq += __shfl_xor(ksq, 32);

    const float mq = sqrtf(qsq);

    float P[4];
    #pragma unroll
    for (int j = 0; j < 4; ++j) {
        float ksg = __shfl(ksq, hi * 4 + j);
        float dsq = fmaxf(qsq + ksg - 2.f * s[j], 0.f);
        dsq = dsq * (1.f + CURV * cosf(sqrtf(dsq + EPS_F)));
        P[j] = mq * sqrtf(ksg) / (dsq + EPS_F);
    }
    float mx = fmaxf(fmaxf(P[0], P[1]), fmaxf(P[2], P[3]));
    mx = fmaxf(mx, __shfl_xor(mx, 16));
    mx = fmaxf(mx, __shfl_xor(mx, 32));
    float sm = 0.f;
    #pragma unroll
    for (int j = 0; j < 4; ++j) { P[j] = expf(P[j] - mx); sm += P[j]; }
    sm += __shfl_xor(sm, 16); sm += __shfl_xor(sm, 32);
    const float inv = 1.f / sm;

    unsigned int w0 = (unsigned)f2bf_bits(P[0] * inv)
                    | ((unsigned)f2bf_bits(P[1] * inv) << 16);
    unsigned int w1 = (unsigned)f2bf_bits(P[2] * inv)
                    | ((unsigned)f2bf_bits(P[3] * inv) << 16);
    const int s0 = lr + (((2 * hi)     & 3) << 4);
    const int s1 = lr + (((2 * hi + 1) & 3) << 4);
    unsigned int a0 = __shfl((int)w0, s0), a1 = __shfl((int)w1, s0);
    unsigned int a2 = __shfl((int)w0, s1), a3 = __shfl((int)w1, s1);
    if (hi >= 2) { a0 = a1 = a2 = a3 = 0; }
    unsigned int pa_u[4] = {a0, a1, a2, a3};
    short8v pa = *(short8v*)pa_u;

    const unsigned short* vb = base + 2048;
    unsigned short* orow = aout + (size_t)p * D_MODEL;
    #pragma unroll
    for (int c = 0; c < 4; ++c) {
        unsigned int bu[4];
        #pragma unroll
        for (int e2 = 0; e2 < 4; ++e2) {
            int g0 = (hi * 8 + e2 * 2) & 15;
            int g1 = (hi * 8 + e2 * 2 + 1) & 15;
            unsigned int lo = vb[g0 * 64 + c * 16 + lr];
            unsigned int hi16 = vb[g1 * 64 + c * 16 + lr];
            bu[e2] = lo | (hi16 << 16);
        }
        short8v bv = *(short8v*)bu;
        f32x4 o = {};
        o = __builtin_amdgcn_mfma_f32_16x16x32_bf16(pa, bv, o, 0, 0, 0);
        #pragma unroll
        for (int j = 0; j < 4; ++j)
            orow[(hi * 4 + j) * 64 + c * 16 + lr] = f2bf_bits(o[j]);
    }
}

// ---------------------------------------------------------------------------
extern "C" void kernel_launch(void* const* d_in, const int* in_sizes, int n_in,
                              void* d_out, int out_size, void* d_ws, size_t ws_size,
                              hipStream_t stream)
{
    const float* x     = (const float*)d_in[0];   // 16384 x 1024
    const float* W_qkv = (const float*)d_in[1];   // 1024 x 3072
    const float* b_qkv = (const float*)d_in[2];   // 3072
    const float* W_out = (const float*)d_in[3];   // 1024 x 1024
    const float* b_out = (const float*)d_in[4];   // 1024
    float* out = (float*)d_out;                   // 16384 x 1024

    // workspace: [0,96M) qkv bf16 | [96M,128M) xb/ab bf16 | Wt1 6M | Wt2 2M
    char* ws = (char*)d_ws;
    unsigned short* qkvb = (unsigned short*)ws;
    unsigned short* xb   = (unsigned short*)(ws + (size_t)M_TOTAL * N_QKV * 2);
    unsigned short* ab   = xb;   // alias: xb dead after GEMM1
    unsigned short* Wt1  = (unsigned short*)(ws + (size_t)M_TOTAL * N_QKV * 2
                                                + (size_t)M_TOTAL * D_MODEL * 2);
    unsigned short* Wt2  = Wt1 + (size_t)N_QKV * D_MODEL;

    // 0a) cast x -> bf16
    {
        int ngroups = M_TOTAL * D_MODEL / 4;
        cast_f32_bf16<<<ngroups / 256, 256, 0, stream>>>(x, xb, ngroups);
    }
    // 0b) transpose+cast weights
    {
        dim3 g(N_QKV / 32, D_MODEL / 32);
        transpose_cast<<<g, 256, 0, stream>>>(W_qkv, Wt1, D_MODEL, N_QKV);
        dim3 g2(D_MODEL / 32, D_MODEL / 32);
        transpose_cast<<<g2, 256, 0, stream>>>(W_out, Wt2, D_MODEL, D_MODEL);
    }

    // 1) qkv = x @ W_qkv + b_qkv  (bf16 out)
    {
        int nbx = N_QKV / 256;                 // 12
        int nwg = (M_TOTAL / 256) * nbx;       // 768 (%8==0)
        gemm256_8ph<1><<<nwg, 512, 0, stream>>>(xb, Wt1, b_qkv, qkvb,
                                                M_TOTAL, N_QKV, D_MODEL, nbx);
    }

    // 2) per-position head attention — 1 wave/position, 4 positions/block
    attn_mfma_kernel<<<M_TOTAL / 4, 256, 0, stream>>>(qkvb, ab);

    // 3) out = ab @ W_out + b_out  (fp32 out)
    {
        int nbx = D_MODEL / 256;               // 4
        int nwg = (M_TOTAL / 256) * nbx;       // 256 (%8==0)
        gemm256_8ph<0><<<nwg, 512, 0, stream>>>(ab, Wt2, b_out, out,
                                                M_TOTAL, D_MODEL, D_MODEL, nbx);
    }
}